// Round 9
// baseline (247.150 us; speedup 1.0000x reference)
//
#include <hip/hip_runtime.h>
#include <math.h>

typedef __bf16 bf16;
typedef __bf16 bf16x4 __attribute__((ext_vector_type(4)));
typedef __bf16 bf16x8 __attribute__((ext_vector_type(8)));
typedef float f32x4 __attribute__((ext_vector_type(4)));

#define NPTS 8192
#define MTOT 16384

static __device__ __forceinline__ float b2f(bf16 x) { return (float)x; }
static __device__ __forceinline__ bf16  f2b(float x) { return (bf16)x; }

// ------------------------------------------------------------ diagnostics --
__global__ void diag_k(float* out, float code)
{
    if (threadIdx.x == 0 && blockIdx.x == 0) out[0] = code;
}

// --------------------------------------------------------------- pack ------
static __device__ __forceinline__ void pack_body(bf16 (*tile)[68],
                                                 const float* __restrict__ src, int Csrc,
                                                 bf16* __restrict__ dst, int ldd,
                                                 int nb, int cb, int b)
{
    const int t = threadIdx.x;
#pragma unroll
    for (int i = 0; i < 8; ++i) {
        int id = t + i * 256;
        int c = id >> 6, n = id & 63;
        int cc = cb + c;
        bf16 v = (bf16)0.0f;
        if (cc < Csrc) v = f2b(src[(size_t)(b * Csrc + cc) * NPTS + nb + n]);
        tile[c][n] = v;
    }
    __syncthreads();
#pragma unroll
    for (int i = 0; i < 8; ++i) {
        int id = t + i * 256;
        int n = id >> 5, c = id & 31;
        dst[(size_t)(b * NPTS + nb + n) * ldd + cb + c] = tile[c][n];
    }
}

// inverse of the monotonic fp32->u32 order transform
static __device__ __forceinline__ float tau32(unsigned u)
{
    unsigned m = 0x80000000u | (unsigned)(~((int)u >> 31));
    return __uint_as_float(u ^ m);
}

// DPP whole-row shift-right-by-1 within 16-lane rows; invalid source -> 0.
static __device__ __forceinline__ unsigned dpp_shr1_u(unsigned x)
{
    return (unsigned)__builtin_amdgcn_update_dpp(0, (int)x, 0x111, 0xf, 0xf, true);
}
static __device__ __forceinline__ int dpp_shr1_i(int x)
{
    return __builtin_amdgcn_update_dpp(0, x, 0x111, 0xf, 0xf, true);
}

// exact 64-bit (dist,idx) 9-min butterfly init over first 64 candidates,
// scattering rank r to lane r (bit-identical to rounds 3-7).
static __device__ __forceinline__ void init9(float d, int lane,
                                             unsigned& kkd, int& idd)
{
    unsigned kd = __float_as_uint(d);
    kd ^= ((unsigned)((int)kd >> 31)) | 0x80000000u;
    unsigned long long key = ((unsigned long long)kd << 32) | (unsigned)lane;
#pragma unroll
    for (int r = 0; r < 9; ++r) {
        unsigned long long m = key;
#pragma unroll
        for (int s = 1; s < 64; s <<= 1) {
            unsigned long long o = __shfl_xor(m, s);
            if (o < m) m = o;
        }
        if (lane == r) {
            kkd = (unsigned)(m >> 32);
            idd = (int)(unsigned)(m & 0xffffffffu);
        }
        if (key == m) key = ~0ull;
    }
}

// lane-distributed sorted insert of all hits in this group (suffix property;
// bit-identical to rounds 3-7's version).
static __device__ __forceinline__ void hits9(float d, int base, float& tau,
                                             unsigned& kkd, int& idd)
{
    unsigned long long mask = __ballot(d <= tau);
    if (mask) {
        do {
            int L = __builtin_ctzll(mask);
            mask &= mask - 1;
            unsigned di = (unsigned)__builtin_amdgcn_readlane(__float_as_int(d), L);
            unsigned kd = di ^ (((unsigned)((int)di >> 31)) | 0x80000000u);
            const int idxn = base + L;
            unsigned kprev = dpp_shr1_u(kkd);
            int      iprev = dpp_shr1_i(idd);
            bool lt  = kd < kkd;
            bool ltp = kd < kprev;   // lane0: kprev==0 -> false
            kkd = lt ? (ltp ? kprev : kd)   : kkd;
            idd = lt ? (ltp ? iprev : idxn) : idd;
        } while (mask);
        tau = tau32((unsigned)__builtin_amdgcn_readlane((int)kkd, 8));
    }
}

// --------------------------------------------------- 32x32 wave-tile MM ----
static __device__ __forceinline__ void mm32(
    f32x4 (&acc)[2][2],
    const bf16* A1, int lda1, int row01, int K1,
    const bf16* A2, int lda2, int row02,
    const bf16* W, int ldw, int K, int ob)
{
    const int lane = threadIdx.x & 63;
    const int q = lane >> 4, r = lane & 15;
    const bf16* Wp = W + (size_t)(ob + r) * ldw + q * 8;
    for (int k = 0; k < K; k += 32) {
        const bf16* Ap; int ld;
        if (k < K1) { ld = lda1; Ap = A1 + (size_t)(row01 + r) * lda1 + q * 8 + k; }
        else        { ld = lda2; Ap = A2 + (size_t)(row02 + r) * lda2 + q * 8 + (k - K1); }
        bf16x8 bv0 = *(const bf16x8*)(Wp + k);
        bf16x8 bv1 = *(const bf16x8*)(Wp + 16 * ldw + k);
        bf16x8 a0 = *(const bf16x8*)(Ap);
        bf16x8 a1 = *(const bf16x8*)(Ap + 16 * ld);
        acc[0][0] = __builtin_amdgcn_mfma_f32_16x16x32_bf16(a0, bv0, acc[0][0], 0, 0, 0);
        acc[1][0] = __builtin_amdgcn_mfma_f32_16x16x32_bf16(a1, bv0, acc[1][0], 0, 0, 0);
        acc[0][1] = __builtin_amdgcn_mfma_f32_16x16x32_bf16(a0, bv1, acc[0][1], 0, 0, 0);
        acc[1][1] = __builtin_amdgcn_mfma_f32_16x16x32_bf16(a1, bv1, acc[1][1], 0, 0, 0);
    }
}

static __device__ __forceinline__ void zacc(f32x4 (&acc)[2][2])
{
    f32x4 z = {0.f, 0.f, 0.f, 0.f};
    acc[0][0] = z; acc[0][1] = z; acc[1][0] = z; acc[1][1] = z;
}

// ------------------------------- 32x16 wave-tile MM (8-wave megarow) -------
static __device__ __forceinline__ void mm16(
    f32x4 (&acc)[2],
    const bf16* A1, int lda1, int row01, int K1,
    const bf16* A2, int lda2, int row02,
    const bf16* W, int ldw, int K, int ob)
{
    const int lane = threadIdx.x & 63;
    const int q = lane >> 4, r = lane & 15;
    const bf16* Wp = W + (size_t)(ob + r) * ldw + q * 8;
    for (int k = 0; k < K; k += 32) {
        const bf16* Ap; int ld;
        if (k < K1) { ld = lda1; Ap = A1 + (size_t)(row01 + r) * lda1 + q * 8 + k; }
        else        { ld = lda2; Ap = A2 + (size_t)(row02 + r) * lda2 + q * 8 + (k - K1); }
        bf16x8 bv0 = *(const bf16x8*)(Wp + k);
        bf16x8 a0 = *(const bf16x8*)(Ap);
        bf16x8 a1 = *(const bf16x8*)(Ap + 16 * ld);
        acc[0] = __builtin_amdgcn_mfma_f32_16x16x32_bf16(a0, bv0, acc[0], 0, 0, 0);
        acc[1] = __builtin_amdgcn_mfma_f32_16x16x32_bf16(a1, bv0, acc[1], 0, 0, 0);
    }
}

static __device__ __forceinline__ void mm16x2(
    f32x4 (&acc)[2], f32x4 (&acc2)[2],
    const bf16* A1, int lda1, int row01, int K1,
    const bf16* A2, int lda2, int row02,
    const bf16* Wa, const bf16* Wb, int ldw, int K, int ob)
{
    const int lane = threadIdx.x & 63;
    const int q = lane >> 4, r = lane & 15;
    const bf16* Wpa = Wa + (size_t)(ob + r) * ldw + q * 8;
    const bf16* Wpb = Wb + (size_t)(ob + r) * ldw + q * 8;
    for (int k = 0; k < K; k += 32) {
        const bf16* Ap; int ld;
        if (k < K1) { ld = lda1; Ap = A1 + (size_t)(row01 + r) * lda1 + q * 8 + k; }
        else        { ld = lda2; Ap = A2 + (size_t)(row02 + r) * lda2 + q * 8 + (k - K1); }
        bf16x8 a0 = *(const bf16x8*)(Ap);
        bf16x8 a1 = *(const bf16x8*)(Ap + 16 * ld);
        bf16x8 ba0 = *(const bf16x8*)(Wpa + k);
        bf16x8 bb0 = *(const bf16x8*)(Wpb + k);
        acc[0]  = __builtin_amdgcn_mfma_f32_16x16x32_bf16(a0, ba0, acc[0], 0, 0, 0);
        acc[1]  = __builtin_amdgcn_mfma_f32_16x16x32_bf16(a1, ba0, acc[1], 0, 0, 0);
        acc2[0] = __builtin_amdgcn_mfma_f32_16x16x32_bf16(a0, bb0, acc2[0], 0, 0, 0);
        acc2[1] = __builtin_amdgcn_mfma_f32_16x16x32_bf16(a1, bb0, acc2[1], 0, 0, 0);
    }
}

static __device__ __forceinline__ void zacc2(f32x4 (&acc)[2])
{
    f32x4 z = {0.f, 0.f, 0.f, 0.f};
    acc[0] = z; acc[1] = z;
}

// ----------------------------- K1: pack what conv12 needs (+ all weights) --
// blocks: 0..47 W0p | 48..687 WTS | 688..1199 CV | 1200..1455 FL |
//         1456..1519 P4 (xyz -> float4 with w = x^2+y^2+z^2)
__global__ __launch_bounds__(256) void pack_a(
    const float* __restrict__ w0, const float* __restrict__ w1,
    const float* __restrict__ wz, const float* __restrict__ wr,
    const float* __restrict__ wq, const float* __restrict__ w2a,
    const float* __restrict__ w2b, const float* __restrict__ rw0,
    const float* __restrict__ rw1, const float* __restrict__ cw0,
    const float* __restrict__ cw1,
    const float* __restrict__ cost, const float* __restrict__ flow,
    const float* __restrict__ xyz,
    bf16* __restrict__ w0p, bf16* __restrict__ wts,
    bf16* __restrict__ CV, bf16* __restrict__ FL,
    float4* __restrict__ P4)
{
    __shared__ __align__(16) bf16 tile[32][68];
    const int bx = blockIdx.x;
    if (bx < 48) {
        int id = bx * 256 + threadIdx.x;
        if (id < 128 * 96) {
            int o = id / 96, c = id - o * 96;
            w0p[id] = (c < 67) ? f2b(w0[o * 67 + c]) : (bf16)0.0f;
        }
    } else if (bx < 688) {
        int id = (bx - 48) * 256 + threadIdx.x;
        if (id < 163840) {
            const float* s; int off;
            if (id < 16384)       { s = w1;  off = 0; }
            else if (id < 49152)  { s = wz;  off = 16384; }
            else if (id < 81920)  { s = wr;  off = 49152; }
            else if (id < 114688) { s = wq;  off = 81920; }
            else if (id < 139264) { s = w2a; off = 114688; }
            else if (id < 147456) { s = w2b; off = 139264; }
            else if (id < 151552) { s = rw0; off = 147456; }
            else if (id < 155648) { s = rw1; off = 151552; }
            else if (id < 159744) { s = cw0; off = 155648; }
            else                  { s = cw1; off = 159744; }
            wts[id] = f2b(s[id - off]);
        }
    } else if (bx < 1200) {
        int l = bx - 688, x = l & 127, r2 = l >> 7;
        pack_body(tile, cost, 64, CV, 64, x * 64, (r2 & 1) * 32, r2 >> 1);
    } else if (bx < 1456) {
        int l = bx - 1200, x = l & 127, b = l >> 7;
        pack_body(tile, flow, 3, FL, 32, x * 64, 0, b);
    } else {
        // P4: same value expression as the old in-kernel staging
        int id = (bx - 1456) * 256 + threadIdx.x;      // 0..16383
        int b = id >> 13, n = id & (NPTS - 1);
        const float* X = xyz + b * 3 * NPTS;
        float x = X[n], y = X[NPTS + n], z = X[2 * NPTS + n];
        P4[id] = make_float4(x, y, z, x * x + y * y + z * z);
    }
}

// -------- K2: knn || conv12 || FE/PT pack || coarse regnet -----------------
// knn blocks 0..1023 (16 queries/block, 4/wave), conv12 1024..1535,
// FE pack 1536..2559, PT pack 2560..3071, coarse 3072..3327.
// knn reads precomputed P4 directly (L2-resident, 256KB): ZERO LDS, ZERO
// barriers, no staging. One coalesced 16B load per group amortized over 4
// queries. Candidate visit order and all FP expressions identical ->
// bit-identical selection.
__global__ __launch_bounds__(256, 5) void knn_conv_packb(
    const float* __restrict__ xyz, const float4* __restrict__ P4,
    const bf16* __restrict__ CV, const bf16* __restrict__ FL,
    const bf16* __restrict__ W0p, const bf16* __restrict__ W1,
    const bf16* __restrict__ CW0, const bf16* __restrict__ CW1,
    const float* __restrict__ b0, const float* __restrict__ bn0,
    const float* __restrict__ b1, const float* __restrict__ bn1,
    const float* __restrict__ cbn0, const float* __restrict__ cbn1,
    const float* __restrict__ cw2, const float* __restrict__ cbn2,
    const float* __restrict__ feats, const float* __restrict__ points,
    bf16* __restrict__ FE, bf16* __restrict__ PT,
    bf16* __restrict__ P2, int* __restrict__ idxg,
    float* __restrict__ coarseG)
{
    __shared__ __align__(16) char smem[18432];
    const int bx = blockIdx.x;
    if (bx < 1024) {
        // ------------------------------ knn (LDS-free) --------------------
        const int t = threadIdx.x, lane = t & 63, w = t >> 6;
        const int q0 = bx * 16 + w * 4;                 // queries q0..q0+3
        const int b = q0 >> 13;
        const float* X = xyz + b * 3 * NPTS;
        const float4* C4 = P4 + (size_t)b * NPTS;

        float qx[4], qy[4], qz[4], qsq[4];
#pragma unroll
        for (int j = 0; j < 4; ++j) {
            int n = (q0 + j) & (NPTS - 1);
            qx[j] = X[n]; qy[j] = X[NPTS + n]; qz[j] = X[2 * NPTS + n];
            qsq[j] = qx[j] * qx[j] + qy[j] * qy[j] + qz[j] * qz[j];
        }
        unsigned kkd[4]; int idd[4]; float tau[4];
#pragma unroll
        for (int j = 0; j < 4; ++j) { kkd[j] = 0xFFFFFFFFu; idd[j] = 0; }

        {   // group 0: exact 64-bit (dist,idx) 9-min init
            float4 c = C4[lane];
#pragma unroll
            for (int j = 0; j < 4; ++j) {
                float d = (qsq[j] + c.w) - 2.0f * (qx[j] * c.x + qy[j] * c.y + qz[j] * c.z);
                init9(d, lane, kkd[j], idd[j]);
                tau[j] = tau32((unsigned)__builtin_amdgcn_readlane((int)kkd[j], 8));
            }
        }
        for (int g = 1; g < 128; ++g) {
            float4 c = C4[g * 64 + lane];
            const int base = g * 64;
#pragma unroll
            for (int j = 0; j < 4; ++j) {
                float d = (qsq[j] + c.w) - 2.0f * (qx[j] * c.x + qy[j] * c.y + qz[j] * c.z);
                hits9(d, base, tau[j], kkd[j], idd[j]);
            }
        }
        if (lane < 9) {
#pragma unroll
            for (int j = 0; j < 4; ++j) {
                int m = idd[j];
                m = ((unsigned)m < (unsigned)NPTS) ? m : 0;
                idxg[(q0 + j) * 9 + lane] = b * NPTS + m;
            }
        }
    } else if (bx < 1536) {
        // --------------------------- conv12 -------------------------------
        bf16 (*P1t)[136] = (bf16 (*)[136])smem;
        const int w = threadIdx.x >> 6, lane = threadIdx.x & 63;
        const int q = lane >> 4, r = lane & 15;
        const int ptb = (bx - 1024) * 32;
        {
            f32x4 acc[2][2]; zacc(acc);
            const int ob = w * 32;
            mm32(acc, CV, 64, ptb, 64, FL, 32, ptb, W0p, 96, 96, ob);
#pragma unroll
            for (int to = 0; to < 2; ++to) {
                const int o = ob + to * 16 + r;
                float bs = b0[o];
                float gg = bn0[o], be = bn0[128 + o], mm = bn0[256 + o];
                float rs = 1.0f / sqrtf(bn0[384 + o] + 1e-5f);
#pragma unroll
                for (int tm = 0; tm < 2; ++tm) {
#pragma unroll
                    for (int rr = 0; rr < 4; ++rr) {
                        const int jl = tm * 16 + q * 4 + rr;
                        float v = acc[tm][to][rr] + bs;
                        v = (v - mm) * rs * gg + be;
                        v = v > 0.f ? v : 0.1f * v;
                        P1t[jl][o] = f2b(v);
                    }
                }
            }
        }
        __syncthreads();
        {
            f32x4 acc[2][2]; zacc(acc);
            const int ob = w * 32;
            mm32(acc, &P1t[0][0], 136, 0, 128, &P1t[0][0], 136, 0, W1, 128, 128, ob);
#pragma unroll
            for (int to = 0; to < 2; ++to) {
                const int o = ob + to * 16 + r;
                float bs = b1[o];
                float gg = bn1[o], be = bn1[128 + o], mm = bn1[256 + o];
                float rs = 1.0f / sqrtf(bn1[384 + o] + 1e-5f);
#pragma unroll
                for (int tm = 0; tm < 2; ++tm) {
#pragma unroll
                    for (int rr = 0; rr < 4; ++rr) {
                        const int jl = tm * 16 + q * 4 + rr;
                        float v = acc[tm][to][rr] + bs;
                        v = (v - mm) * rs * gg + be;
                        v = v > 0.f ? v : 0.1f * v;
                        P2[(size_t)(ptb + jl) * 128 + o] = f2b(v);
                    }
                }
            }
        }
    } else if (bx < 2560) {
        bf16 (*tile)[68] = (bf16 (*)[68])smem;
        int l = bx - 1536, x = l & 127, r2 = l >> 7;
        pack_body(tile, feats, 128, FE, 128, x * 64, (r2 & 3) * 32, r2 >> 2);
    } else if (bx < 3072) {
        bf16 (*tile)[68] = (bf16 (*)[68])smem;
        int l = bx - 2560, x = l & 127, r2 = l >> 7;
        pack_body(tile, points, 64, PT, 64, x * 64, (r2 & 1) * 32, r2 >> 1);
    } else {
        // --------- coarse = reg(cost_volume): 64 points/block --------------
        bf16 (*C1t)[72] = (bf16 (*)[72])smem;             // [64][72]
        bf16 (*C2t)[72] = (bf16 (*)[72])(smem + 9216);    // [64][72]
        const int w = threadIdx.x >> 6, lane = threadIdx.x & 63;
        const int q = lane >> 4, r = lane & 15;
        const int row0 = (w >> 1) * 32;
        const int pt0 = (bx - 3072) * 64 + row0;
        const int ob = (w & 1) * 32;
        {
            f32x4 acc[2][2]; zacc(acc);
            mm32(acc, CV, 64, pt0, 64, CV, 64, pt0, CW0, 64, 64, ob);
#pragma unroll
            for (int to = 0; to < 2; ++to) {
                const int o = ob + to * 16 + r;
                float gg = cbn0[o], be = cbn0[64 + o], mm = cbn0[128 + o];
                float rs = 1.0f / sqrtf(cbn0[192 + o] + 1e-5f);
#pragma unroll
                for (int tm = 0; tm < 2; ++tm)
#pragma unroll
                    for (int rr = 0; rr < 4; ++rr) {
                        const int jl = tm * 16 + q * 4 + rr;
                        float v = acc[tm][to][rr];
                        v = (v - mm) * rs * gg + be;
                        C1t[row0 + jl][o] = f2b(fmaxf(v, 0.f));
                    }
            }
        }
        __syncthreads();
        {
            f32x4 acc[2][2]; zacc(acc);
            mm32(acc, &C1t[0][0], 72, row0, 64, &C1t[0][0], 72, row0, CW1, 64, 64, ob);
#pragma unroll
            for (int to = 0; to < 2; ++to) {
                const int o = ob + to * 16 + r;
                float gg = cbn1[o], be = cbn1[64 + o], mm = cbn1[128 + o];
                float rs = 1.0f / sqrtf(cbn1[192 + o] + 1e-5f);
#pragma unroll
                for (int tm = 0; tm < 2; ++tm)
#pragma unroll
                    for (int rr = 0; rr < 4; ++rr) {
                        const int jl = tm * 16 + q * 4 + rr;
                        float v = acc[tm][to][rr];
                        v = (v - mm) * rs * gg + be;
                        C2t[row0 + jl][o] = f2b(fmaxf(v, 0.f));
                    }
            }
        }
        __syncthreads();
        if (threadIdx.x < 64) {
            const int jl = threadIdx.x;
            const int j = (bx - 3072) * 64 + jl;
            float dc = 0.f;
#pragma unroll
            for (int c = 0; c < 64; ++c) dc += cw2[c] * b2f(C2t[jl][c]);
            float coarse = (dc - cbn2[2]) / sqrtf(cbn2[3] + 1e-5f) * cbn2[0] + cbn2[1];
            coarseG[j] = fmaxf(coarse, 0.f);
        }
    }
}

// ------------------------------ K3: fused gather + row-local tail ----------
struct MRP {
    const bf16 *P2, *FE, *PT;
    const int  *idx;
    const bf16 *WZ, *WR, *WQ, *W2A, *W2B, *RW0, *RW1;
    const float *bz, *br, *bq, *b2a, *b2b;
    const float *rbn0, *rbn1;
    const float *rw2, *rbn2, *wfc, *bfc, *flow, *coarse;
    float* out;
};

// block = 32 points, 8 waves (512 thr). Stage 0: FE/PT tiles -> LDS + 9-NN
// gather-max (16B loads, one row/thread) -> X1t. Then zr (mm16x2) -> gq ->
// g2a -> g2b -> R1 -> R2 -> head; every mm operand reads LDS. Per-output
// accumulation chains bit-identical.
__global__ __launch_bounds__(512) void megarow(MRP p)
{
    __shared__ __align__(16) bf16 Zt[32][136], RHt[32][136], HPt[32][136], X1t[32][136];
    __shared__ __align__(16) bf16 FEt[32][136];
    __shared__ __align__(16) bf16 X2t[32][72], R1t[32][72], R2t[32][72], PTt[32][72];
    __shared__ int idxt[32][9];
    const int w = threadIdx.x >> 6, lane = threadIdx.x & 63;
    const int q = lane >> 4, r = lane & 15;
    const int ptb = blockIdx.x * 32;

    // stage 0a: idx tile + FE/PT tiles into LDS
    if (threadIdx.x < 288) {
        int jl = threadIdx.x / 9, k = threadIdx.x - jl * 9;
        int m = p.idx[(ptb + jl) * 9 + k];
        idxt[jl][k] = ((unsigned)m < (unsigned)MTOT) ? m : 0;
    }
    {
        const int row = threadIdx.x >> 4;
        const int c8 = (threadIdx.x & 15) * 8;
        *(bf16x8*)&FEt[row][c8] = *(const bf16x8*)(p.FE + (size_t)(ptb + row) * 128 + c8);
        const int c4 = (threadIdx.x & 15) * 4;
        *(bf16x4*)&PTt[row][c4] = *(const bf16x4*)(p.PT + (size_t)(ptb + row) * 64 + c4);
    }
    __syncthreads();
    // stage 0b: gather-max H tile (16B loads; same per-channel fmax chains)
    {
        const int c8 = (threadIdx.x & 15) * 8;
        const int jl = threadIdx.x >> 4;             // row 0..31
        float mx0 = -__builtin_inff(), mx1 = -__builtin_inff();
        float mx2 = -__builtin_inff(), mx3 = -__builtin_inff();
        float mx4 = -__builtin_inff(), mx5 = -__builtin_inff();
        float mx6 = -__builtin_inff(), mx7 = -__builtin_inff();
#pragma unroll
        for (int k = 0; k < 9; ++k) {
            bf16x8 v = *(const bf16x8*)(p.P2 + (size_t)idxt[jl][k] * 128 + c8);
            mx0 = fmaxf(mx0, b2f(v[0]));
            mx1 = fmaxf(mx1, b2f(v[1]));
            mx2 = fmaxf(mx2, b2f(v[2]));
            mx3 = fmaxf(mx3, b2f(v[3]));
            mx4 = fmaxf(mx4, b2f(v[4]));
            mx5 = fmaxf(mx5, b2f(v[5]));
            mx6 = fmaxf(mx6, b2f(v[6]));
            mx7 = fmaxf(mx7, b2f(v[7]));
        }
        bf16x8 st;
        st[0] = f2b(mx0); st[1] = f2b(mx1); st[2] = f2b(mx2); st[3] = f2b(mx3);
        st[4] = f2b(mx4); st[5] = f2b(mx5); st[6] = f2b(mx6); st[7] = f2b(mx7);
        *(bf16x8*)&X1t[jl][c8] = st;
    }
    __syncthreads();

    // D: GRU gates z, r.h  (X1t == H tile); A loaded once per wave, all LDS
    {
        const int ob = w * 16;
        f32x4 acc[2], acc2[2]; zacc2(acc); zacc2(acc2);
        mm16x2(acc, acc2, &X1t[0][0], 136, 0, 128, &FEt[0][0], 136, 0,
               p.WZ, p.WR, 256, 256, ob);
        const int o = ob + r;
        const float bsz = p.bz[o];
#pragma unroll
        for (int tm = 0; tm < 2; ++tm)
#pragma unroll
            for (int rr = 0; rr < 4; ++rr) {
                const int jl = tm * 16 + q * 4 + rr;
                float v = acc[tm][rr] + bsz;
                Zt[jl][o] = f2b(1.0f / (1.0f + expf(-v)));
            }
        const float bsr = p.br[o];
#pragma unroll
        for (int tm = 0; tm < 2; ++tm)
#pragma unroll
            for (int rr = 0; rr < 4; ++rr) {
                const int jl = tm * 16 + q * 4 + rr;
                float v = acc2[tm][rr] + bsr;
                v = 1.0f / (1.0f + expf(-v));
                RHt[jl][o] = f2b(v * b2f(X1t[jl][o]));
            }
    }
    __syncthreads();
    // E: q = tanh(...); h' = (1-z)h + z q  -> HPt
    {
        const int ob = w * 16;
        f32x4 acc[2]; zacc2(acc);
        mm16(acc, &RHt[0][0], 136, 0, 128, &FEt[0][0], 136, 0, p.WQ, 256, 256, ob);
        const int o = ob + r;
        const float bs = p.bq[o];
#pragma unroll
        for (int tm = 0; tm < 2; ++tm)
#pragma unroll
            for (int rr = 0; rr < 4; ++rr) {
                const int jl = tm * 16 + q * 4 + rr;
                float v = acc[tm][rr] + bs;
                float qv = tanhf(v);
                float z = b2f(Zt[jl][o]);
                float h = b2f(X1t[jl][o]);
                HPt[jl][o] = f2b((1.0f - z) * h + z * qv);
            }
    }
    __syncthreads();
    // F: x1 = lrelu(w2a . [points | h'])  (overwrites X1t — H dead now)
    {
        const int ob = w * 16;
        f32x4 acc[2]; zacc2(acc);
        mm16(acc, &PTt[0][0], 72, 0, 64, &HPt[0][0], 136, 0, p.W2A, 192, 192, ob);
        const int o = ob + r;
        const float bs = p.b2a[o];
#pragma unroll
        for (int tm = 0; tm < 2; ++tm)
#pragma unroll
            for (int rr = 0; rr < 4; ++rr) {
                const int jl = tm * 16 + q * 4 + rr;
                float v = acc[tm][rr] + bs;
                X1t[jl][o] = f2b(v > 0.f ? v : 0.1f * v);
            }
    }
    __syncthreads();
    // G: waves 0-3: x2 = lrelu(w2b . x1) (+ out x-section)
    if (w < 4) {
        const int ob = w * 16;
        f32x4 acc[2]; zacc2(acc);
        mm16(acc, &X1t[0][0], 136, 0, 128, &X1t[0][0], 136, 0, p.W2B, 128, 128, ob);
        const int o = ob + r;
        const float bs = p.b2b[o];
#pragma unroll
        for (int tm = 0; tm < 2; ++tm)
#pragma unroll
            for (int rr = 0; rr < 4; ++rr) {
                const int jl = tm * 16 + q * 4 + rr;
                float v = acc[tm][rr] + bs;
                v = v > 0.f ? v : 0.1f * v;
                X2t[jl][o] = f2b(v);
                const int j = ptb + jl, bb = j >> 13, nn = j & (NPTS - 1);
                p.out[(size_t)bb * 64 * NPTS + (size_t)o * NPTS + nn] = v;
            }
    }
    __syncthreads();
    // H: waves 0-3: R1 = reg(x2)
    if (w < 4) {
        const int ob = w * 16;
        f32x4 acc[2]; zacc2(acc);
        mm16(acc, &X2t[0][0], 72, 0, 64, &X2t[0][0], 72, 0, p.RW0, 64, 64, ob);
        const int o = ob + r;
        float gg = p.rbn0[o], be = p.rbn0[64 + o], mm = p.rbn0[128 + o];
        float rs = 1.0f / sqrtf(p.rbn0[192 + o] + 1e-5f);
#pragma unroll
        for (int tm = 0; tm < 2; ++tm)
#pragma unroll
            for (int rr = 0; rr < 4; ++rr) {
                const int jl = tm * 16 + q * 4 + rr;
                float v = acc[tm][rr];
                v = (v - mm) * rs * gg + be;
                R1t[jl][o] = f2b(fmaxf(v, 0.f));
            }
    }
    __syncthreads();
    // I: waves 0-3: R2 = reg(R1)
    if (w < 4) {
        const int ob = w * 16;
        f32x4 acc[2]; zacc2(acc);
        mm16(acc, &R1t[0][0], 72, 0, 64, &R1t[0][0], 72, 0, p.RW1, 64, 64, ob);
        const int o = ob + r;
        float gg = p.rbn1[o], be = p.rbn1[64 + o], mm = p.rbn1[128 + o];
        float rs = 1.0f / sqrtf(p.rbn1[192 + o] + 1e-5f);
#pragma unroll
        for (int tm = 0; tm < 2; ++tm)
#pragma unroll
            for (int rr = 0; rr < 4; ++rr) {
                const int jl = tm * 16 + q * 4 + rr;
                float v = acc[tm][rr];
                v = (v - mm) * rs * gg + be;
                R2t[jl][o] = f2b(fmaxf(v, 0.f));
            }
    }
    __syncthreads();
    // J: head fuse (threads 0..31, one point each)
    if (threadIdx.x < 32) {
        const int jl = threadIdx.x, j = ptb + jl;
        const int b = j >> 13, n = j & (NPTS - 1);
        float dr = 0.f, p0 = 0.f, p1 = 0.f, p2 = 0.f;
#pragma unroll
        for (int c = 0; c < 64; ++c) {
            float x = b2f(X2t[jl][c]);
            dr += p.rw2[c] * b2f(R2t[jl][c]);
            p0 += p.wfc[c] * x;
            p1 += p.wfc[64 + c] * x;
            p2 += p.wfc[128 + c] * x;
        }
        float refine = (dr - p.rbn2[2]) / sqrtf(p.rbn2[3] + 1e-5f) * p.rbn2[0] + p.rbn2[1];
        refine = fmaxf(refine, 0.f);
        const float coarse = p.coarse[j];
        p0 += p.bfc[0]; p1 += p.bfc[1]; p2 += p.bfc[2];
        const float f0 = p.flow[(size_t)b * 3 * NPTS + n];
        const float f1 = p.flow[(size_t)b * 3 * NPTS + NPTS + n];
        const float f2v = p.flow[(size_t)b * 3 * NPTS + 2 * NPTS + n];
        float o0 = fminf(fmaxf(coarse * f0 + refine * p0, -20.f), 20.f);
        float o1 = fminf(fmaxf(coarse * f1 + refine * p1, -20.f), 20.f);
        float o2 = fminf(fmaxf(coarse * f2v + refine * p2, -20.f), 20.f);
        float* ro = p.out + 1048576;
        ro[(size_t)b * 3 * NPTS + n] = o0;
        ro[(size_t)b * 3 * NPTS + NPTS + n] = o1;
        ro[(size_t)b * 3 * NPTS + 2 * NPTS + n] = o2;
    }
}

// -------------------------------------------------------------- launch -----
// Workspace (18,767,872 B):
//   W0p @0 | WTS @24,576 | idxg @352,256 | CV @942,080 | FL @3,039,232
//   FE @4,087,808 | PT @8,282,112 | P2 @10,379,264 | coarse @14,573,568
//   P4 @14,639,104 (262,144 B, float4 x 16384)
extern "C" void kernel_launch(void* const* d_in, const int* in_sizes, int n_in,
                              void* d_out, int out_size, void* d_ws, size_t ws_size,
                              hipStream_t stream)
{
    static const int EXP[35] = {
        49152, 1048576, 1048576, 2097152, 49152,
        8576, 128, 512, 16384, 128, 512,
        32768, 128, 32768, 128, 32768, 128,
        24576, 128, 8192, 64, 192, 3,
        4096, 256, 4096, 256, 64, 4,
        4096, 256, 4096, 256, 64, 4 };
    float code = 0.f;
    if (n_in != 35) code = 900.f;
    else if (out_size != 1097728) code = 950.f;
    else if (ws_size < 18767872u) code = 980.f;
    else { for (int i = 0; i < 35; ++i) if (in_sizes[i] != EXP[i]) { code = 1000.f + 4.f * i; break; } }
    if (code != 0.f) { diag_k<<<dim3(1), dim3(64), 0, stream>>>((float*)d_out, code); return; }

    const float* xyz    = (const float*)d_in[0];
    const float* points = (const float*)d_in[1];
    const float* cost   = (const float*)d_in[2];
    const float* feats  = (const float*)d_in[3];
    const float* flow   = (const float*)d_in[4];
    const float* w0     = (const float*)d_in[5];
    const float* b0     = (const float*)d_in[6];
    const float* bn0    = (const float*)d_in[7];
    const float* w1     = (const float*)d_in[8];
    const float* b1     = (const float*)d_in[9];
    const float* bn1    = (const float*)d_in[10];
    const float* wz     = (const float*)d_in[11];
    const float* bz     = (const float*)d_in[12];
    const float* wr     = (const float*)d_in[13];
    const float* br     = (const float*)d_in[14];
    const float* wq     = (const float*)d_in[15];
    const float* bq     = (const float*)d_in[16];
    const float* w2a    = (const float*)d_in[17];
    const float* b2a    = (const float*)d_in[18];
    const float* w2b    = (const float*)d_in[19];
    const float* b2b    = (const float*)d_in[20];
    const float* wfc    = (const float*)d_in[21];
    const float* bfc    = (const float*)d_in[22];
    const float* rw0    = (const float*)d_in[23];
    const float* rbn0   = (const float*)d_in[24];
    const float* rw1    = (const float*)d_in[25];
    const float* rbn1   = (const float*)d_in[26];
    const float* rw2    = (const float*)d_in[27];
    const float* rbn2   = (const float*)d_in[28];
    const float* cw0    = (const float*)d_in[29];
    const float* cbn0   = (const float*)d_in[30];
    const float* cw1    = (const float*)d_in[31];
    const float* cbn1   = (const float*)d_in[32];
    const float* cw2    = (const float*)d_in[33];
    const float* cbn2   = (const float*)d_in[34];

    char* ws = (char*)d_ws;
    bf16*   W0p  = (bf16*)(ws + 0);
    bf16*   WTS  = (bf16*)(ws + 24576);
    int*    idxg = (int*) (ws + 352256);
    bf16*   CV   = (bf16*)(ws + 942080);
    bf16*   FL   = (bf16*)(ws + 3039232);
    bf16*   FE   = (bf16*)(ws + 4087808);
    bf16*   PT   = (bf16*)(ws + 8282112);
    bf16*   P2   = (bf16*)(ws + 10379264);
    float*  CO   = (float*)(ws + 14573568);
    float4* P4   = (float4*)(ws + 14639104);

    bf16* W1  = WTS;
    bf16* WZ  = WTS + 16384;
    bf16* WR  = WTS + 49152;
    bf16* WQ  = WTS + 81920;
    bf16* W2A = WTS + 114688;
    bf16* W2B = WTS + 139264;
    bf16* RW0 = WTS + 147456;
    bf16* RW1 = WTS + 151552;
    bf16* CW0 = WTS + 155648;
    bf16* CW1 = WTS + 159744;

    float* out = (float*)d_out;

    /*1*/ pack_a<<<dim3(1520), dim3(256), 0, stream>>>(
              w0, w1, wz, wr, wq, w2a, w2b, rw0, rw1, cw0, cw1,
              cost, flow, xyz, W0p, WTS, CV, FL, P4);
    /*2*/ knn_conv_packb<<<dim3(3328), dim3(256), 0, stream>>>(
              xyz, P4, CV, FL, W0p, W1, CW0, CW1,
              b0, bn0, b1, bn1, cbn0, cbn1, cw2, cbn2,
              feats, points, FE, PT, P2, idxg, CO);
    /*3*/ MRP mp;
          mp.P2 = P2; mp.FE = FE; mp.PT = PT; mp.idx = idxg;
          mp.WZ = WZ; mp.WR = WR; mp.WQ = WQ; mp.W2A = W2A; mp.W2B = W2B;
          mp.RW0 = RW0; mp.RW1 = RW1;
          mp.bz = bz; mp.br = br; mp.bq = bq; mp.b2a = b2a; mp.b2b = b2b;
          mp.rbn0 = rbn0; mp.rbn1 = rbn1;
          mp.rw2 = rw2; mp.rbn2 = rbn2;
          mp.wfc = wfc; mp.bfc = bfc; mp.flow = flow; mp.coarse = CO;
          mp.out = out;
          megarow<<<dim3(512), dim3(512), 0, stream>>>(mp);

    (void)n_in;
}

// Round 10
// 228.785 us; speedup vs baseline: 1.0803x; 1.0803x over previous
//
#include <hip/hip_runtime.h>
#include <math.h>

typedef __bf16 bf16;
typedef __bf16 bf16x4 __attribute__((ext_vector_type(4)));
typedef __bf16 bf16x8 __attribute__((ext_vector_type(8)));
typedef float f32x4 __attribute__((ext_vector_type(4)));

#define NPTS 8192
#define MTOT 16384

static __device__ __forceinline__ float b2f(bf16 x) { return (float)x; }
static __device__ __forceinline__ bf16  f2b(float x) { return (bf16)x; }

// ------------------------------------------------------------ diagnostics --
__global__ void diag_k(float* out, float code)
{
    if (threadIdx.x == 0 && blockIdx.x == 0) out[0] = code;
}

// --------------------------------------------------------------- pack ------
static __device__ __forceinline__ void pack_body(bf16 (*tile)[68],
                                                 const float* __restrict__ src, int Csrc,
                                                 bf16* __restrict__ dst, int ldd,
                                                 int nb, int cb, int b)
{
    const int t = threadIdx.x;
#pragma unroll
    for (int i = 0; i < 8; ++i) {
        int id = t + i * 256;
        int c = id >> 6, n = id & 63;
        int cc = cb + c;
        bf16 v = (bf16)0.0f;
        if (cc < Csrc) v = f2b(src[(size_t)(b * Csrc + cc) * NPTS + nb + n]);
        tile[c][n] = v;
    }
    __syncthreads();
#pragma unroll
    for (int i = 0; i < 8; ++i) {
        int id = t + i * 256;
        int n = id >> 5, c = id & 31;
        dst[(size_t)(b * NPTS + nb + n) * ldd + cb + c] = tile[c][n];
    }
}

// inverse of the monotonic fp32->u32 order transform
static __device__ __forceinline__ float tau32(unsigned u)
{
    unsigned m = 0x80000000u | (unsigned)(~((int)u >> 31));
    return __uint_as_float(u ^ m);
}

// DPP whole-row shift-right-by-1 within 16-lane rows; invalid source -> 0.
static __device__ __forceinline__ unsigned dpp_shr1_u(unsigned x)
{
    return (unsigned)__builtin_amdgcn_update_dpp(0, (int)x, 0x111, 0xf, 0xf, true);
}
static __device__ __forceinline__ int dpp_shr1_i(int x)
{
    return __builtin_amdgcn_update_dpp(0, x, 0x111, 0xf, 0xf, true);
}

// exact 64-bit (dist,idx) 9-min butterfly init over first 64 candidates,
// scattering rank r to lane r (bit-identical to rounds 3-7).
static __device__ __forceinline__ void init9(float d, int lane,
                                             unsigned& kkd, int& idd)
{
    unsigned kd = __float_as_uint(d);
    kd ^= ((unsigned)((int)kd >> 31)) | 0x80000000u;
    unsigned long long key = ((unsigned long long)kd << 32) | (unsigned)lane;
#pragma unroll
    for (int r = 0; r < 9; ++r) {
        unsigned long long m = key;
#pragma unroll
        for (int s = 1; s < 64; s <<= 1) {
            unsigned long long o = __shfl_xor(m, s);
            if (o < m) m = o;
        }
        if (lane == r) {
            kkd = (unsigned)(m >> 32);
            idd = (int)(unsigned)(m & 0xffffffffu);
        }
        if (key == m) key = ~0ull;
    }
}

// lane-distributed sorted insert of all hits in this group (suffix property;
// bit-identical to rounds 3-7's version).
static __device__ __forceinline__ void hits9(float d, int base, float& tau,
                                             unsigned& kkd, int& idd)
{
    unsigned long long mask = __ballot(d <= tau);
    if (mask) {
        do {
            int L = __builtin_ctzll(mask);
            mask &= mask - 1;
            unsigned di = (unsigned)__builtin_amdgcn_readlane(__float_as_int(d), L);
            unsigned kd = di ^ (((unsigned)((int)di >> 31)) | 0x80000000u);
            const int idxn = base + L;
            unsigned kprev = dpp_shr1_u(kkd);
            int      iprev = dpp_shr1_i(idd);
            bool lt  = kd < kkd;
            bool ltp = kd < kprev;   // lane0: kprev==0 -> false
            kkd = lt ? (ltp ? kprev : kd)   : kkd;
            idd = lt ? (ltp ? iprev : idxn) : idd;
        } while (mask);
        tau = tau32((unsigned)__builtin_amdgcn_readlane((int)kkd, 8));
    }
}

// --------------------------------------------------- 32x32 wave-tile MM ----
static __device__ __forceinline__ void mm32(
    f32x4 (&acc)[2][2],
    const bf16* A1, int lda1, int row01, int K1,
    const bf16* A2, int lda2, int row02,
    const bf16* W, int ldw, int K, int ob)
{
    const int lane = threadIdx.x & 63;
    const int q = lane >> 4, r = lane & 15;
    const bf16* Wp = W + (size_t)(ob + r) * ldw + q * 8;
    for (int k = 0; k < K; k += 32) {
        const bf16* Ap; int ld;
        if (k < K1) { ld = lda1; Ap = A1 + (size_t)(row01 + r) * lda1 + q * 8 + k; }
        else        { ld = lda2; Ap = A2 + (size_t)(row02 + r) * lda2 + q * 8 + (k - K1); }
        bf16x8 bv0 = *(const bf16x8*)(Wp + k);
        bf16x8 bv1 = *(const bf16x8*)(Wp + 16 * ldw + k);
        bf16x8 a0 = *(const bf16x8*)(Ap);
        bf16x8 a1 = *(const bf16x8*)(Ap + 16 * ld);
        acc[0][0] = __builtin_amdgcn_mfma_f32_16x16x32_bf16(a0, bv0, acc[0][0], 0, 0, 0);
        acc[1][0] = __builtin_amdgcn_mfma_f32_16x16x32_bf16(a1, bv0, acc[1][0], 0, 0, 0);
        acc[0][1] = __builtin_amdgcn_mfma_f32_16x16x32_bf16(a0, bv1, acc[0][1], 0, 0, 0);
        acc[1][1] = __builtin_amdgcn_mfma_f32_16x16x32_bf16(a1, bv1, acc[1][1], 0, 0, 0);
    }
}

static __device__ __forceinline__ void zacc(f32x4 (&acc)[2][2])
{
    f32x4 z = {0.f, 0.f, 0.f, 0.f};
    acc[0][0] = z; acc[0][1] = z; acc[1][0] = z; acc[1][1] = z;
}

// ------------------------------- 32x16 wave-tile MM (8-wave megarow) -------
static __device__ __forceinline__ void mm16(
    f32x4 (&acc)[2],
    const bf16* A1, int lda1, int row01, int K1,
    const bf16* A2, int lda2, int row02,
    const bf16* W, int ldw, int K, int ob)
{
    const int lane = threadIdx.x & 63;
    const int q = lane >> 4, r = lane & 15;
    const bf16* Wp = W + (size_t)(ob + r) * ldw + q * 8;
    for (int k = 0; k < K; k += 32) {
        const bf16* Ap; int ld;
        if (k < K1) { ld = lda1; Ap = A1 + (size_t)(row01 + r) * lda1 + q * 8 + k; }
        else        { ld = lda2; Ap = A2 + (size_t)(row02 + r) * lda2 + q * 8 + (k - K1); }
        bf16x8 bv0 = *(const bf16x8*)(Wp + k);
        bf16x8 a0 = *(const bf16x8*)(Ap);
        bf16x8 a1 = *(const bf16x8*)(Ap + 16 * ld);
        acc[0] = __builtin_amdgcn_mfma_f32_16x16x32_bf16(a0, bv0, acc[0], 0, 0, 0);
        acc[1] = __builtin_amdgcn_mfma_f32_16x16x32_bf16(a1, bv0, acc[1], 0, 0, 0);
    }
}

static __device__ __forceinline__ void mm16x2(
    f32x4 (&acc)[2], f32x4 (&acc2)[2],
    const bf16* A1, int lda1, int row01, int K1,
    const bf16* A2, int lda2, int row02,
    const bf16* Wa, const bf16* Wb, int ldw, int K, int ob)
{
    const int lane = threadIdx.x & 63;
    const int q = lane >> 4, r = lane & 15;
    const bf16* Wpa = Wa + (size_t)(ob + r) * ldw + q * 8;
    const bf16* Wpb = Wb + (size_t)(ob + r) * ldw + q * 8;
    for (int k = 0; k < K; k += 32) {
        const bf16* Ap; int ld;
        if (k < K1) { ld = lda1; Ap = A1 + (size_t)(row01 + r) * lda1 + q * 8 + k; }
        else        { ld = lda2; Ap = A2 + (size_t)(row02 + r) * lda2 + q * 8 + (k - K1); }
        bf16x8 a0 = *(const bf16x8*)(Ap);
        bf16x8 a1 = *(const bf16x8*)(Ap + 16 * ld);
        bf16x8 ba0 = *(const bf16x8*)(Wpa + k);
        bf16x8 bb0 = *(const bf16x8*)(Wpb + k);
        acc[0]  = __builtin_amdgcn_mfma_f32_16x16x32_bf16(a0, ba0, acc[0], 0, 0, 0);
        acc[1]  = __builtin_amdgcn_mfma_f32_16x16x32_bf16(a1, ba0, acc[1], 0, 0, 0);
        acc2[0] = __builtin_amdgcn_mfma_f32_16x16x32_bf16(a0, bb0, acc2[0], 0, 0, 0);
        acc2[1] = __builtin_amdgcn_mfma_f32_16x16x32_bf16(a1, bb0, acc2[1], 0, 0, 0);
    }
}

static __device__ __forceinline__ void zacc2(f32x4 (&acc)[2])
{
    f32x4 z = {0.f, 0.f, 0.f, 0.f};
    acc[0] = z; acc[1] = z;
}

// ----------------------------- K1: pack what conv12 needs (+ all weights) --
// blocks: 0..47 W0p | 48..687 WTS | 688..1199 CV | 1200..1455 FL
__global__ __launch_bounds__(256) void pack_a(
    const float* __restrict__ w0, const float* __restrict__ w1,
    const float* __restrict__ wz, const float* __restrict__ wr,
    const float* __restrict__ wq, const float* __restrict__ w2a,
    const float* __restrict__ w2b, const float* __restrict__ rw0,
    const float* __restrict__ rw1, const float* __restrict__ cw0,
    const float* __restrict__ cw1,
    const float* __restrict__ cost, const float* __restrict__ flow,
    bf16* __restrict__ w0p, bf16* __restrict__ wts,
    bf16* __restrict__ CV, bf16* __restrict__ FL)
{
    __shared__ __align__(16) bf16 tile[32][68];
    const int bx = blockIdx.x;
    if (bx < 48) {
        int id = bx * 256 + threadIdx.x;
        if (id < 128 * 96) {
            int o = id / 96, c = id - o * 96;
            w0p[id] = (c < 67) ? f2b(w0[o * 67 + c]) : (bf16)0.0f;
        }
    } else if (bx < 688) {
        int id = (bx - 48) * 256 + threadIdx.x;
        if (id < 163840) {
            const float* s; int off;
            if (id < 16384)       { s = w1;  off = 0; }
            else if (id < 49152)  { s = wz;  off = 16384; }
            else if (id < 81920)  { s = wr;  off = 49152; }
            else if (id < 114688) { s = wq;  off = 81920; }
            else if (id < 139264) { s = w2a; off = 114688; }
            else if (id < 147456) { s = w2b; off = 139264; }
            else if (id < 151552) { s = rw0; off = 147456; }
            else if (id < 155648) { s = rw1; off = 151552; }
            else if (id < 159744) { s = cw0; off = 155648; }
            else                  { s = cw1; off = 159744; }
            wts[id] = f2b(s[id - off]);
        }
    } else if (bx < 1200) {
        int l = bx - 688, x = l & 127, r2 = l >> 7;
        pack_body(tile, cost, 64, CV, 64, x * 64, (r2 & 1) * 32, r2 >> 1);
    } else {
        int l = bx - 1200, x = l & 127, b = l >> 7;
        pack_body(tile, flow, 3, FL, 32, x * 64, 0, b);
    }
}

// -------- K2: knn || conv12 || FE/PT pack || coarse regnet -----------------
// knn blocks 0..2047 (8 queries/block, 2/wave), conv12 2048..2559,
// FE pack 2560..3583, PT pack 3584..4095, coarse 4096..4351.
// knn: each wave serves TWO queries (qid, qid+4 — same batch since
// 8192%8==0) so the shared per-group cost (LDS read + loop) amortizes over
// two lists, and chunk staging halves chip-wide. Candidate visit order per
// query unchanged -> bit-identical results. LDS-staged chunks are
// load-bearing (R9: LDS-free L2 scan regressed 84->96 µs — 8x L2 traffic
// amplification + latency on the ballot-dependent load).
__global__ __launch_bounds__(256, 5) void knn_conv_packb(
    const float* __restrict__ xyz, const float* __restrict__ feats,
    const float* __restrict__ points,
    const bf16* __restrict__ CV, const bf16* __restrict__ FL,
    const bf16* __restrict__ W0p, const bf16* __restrict__ W1,
    const bf16* __restrict__ CW0, const bf16* __restrict__ CW1,
    const float* __restrict__ b0, const float* __restrict__ bn0,
    const float* __restrict__ b1, const float* __restrict__ bn1,
    const float* __restrict__ cbn0, const float* __restrict__ cbn1,
    const float* __restrict__ cw2, const float* __restrict__ cbn2,
    bf16* __restrict__ FE, bf16* __restrict__ PT,
    bf16* __restrict__ P2, int* __restrict__ idxg,
    float* __restrict__ coarseG)
{
    __shared__ __align__(16) char smem[18432];
    const int bx = blockIdx.x;
    if (bx < 2048) {
        // ------------------------------ knn -------------------------------
        float4* pts = (float4*)smem;
        const int t = threadIdx.x, lane = t & 63, w = t >> 6;
        const int qA = bx * 8 + w, qB = qA + 4;
        const int b = qA >> 13;
        const float* X = xyz + b * 3 * NPTS;
        const int nA = qA & (NPTS - 1), nB = qB & (NPTS - 1);
        const float qxA = X[nA], qyA = X[NPTS + nA], qzA = X[2 * NPTS + nA];
        const float qxB = X[nB], qyB = X[NPTS + nB], qzB = X[2 * NPTS + nB];
        const float qsqA = qxA * qxA + qyA * qyA + qzA * qzA;
        const float qsqB = qxB * qxB + qyB * qyB + qzB * qzB;

        unsigned kkdA = 0xFFFFFFFFu, kkdB = 0xFFFFFFFFu;
        int      iddA = 0, iddB = 0;
        float tauA = __builtin_inff(), tauB = __builtin_inff();

        float nx[4], ny[4], nz[4];
        // preload chunk 0 into regs, stage to LDS
#pragma unroll
        for (int r2 = 0; r2 < 4; ++r2) {
            int ci = t + r2 * 256;
            nx[r2] = X[ci]; ny[r2] = X[NPTS + ci]; nz[r2] = X[2 * NPTS + ci];
        }
#pragma unroll
        for (int r2 = 0; r2 < 4; ++r2) {
            int i2 = t + r2 * 256;
            pts[i2] = make_float4(nx[r2], ny[r2], nz[r2],
                                  nx[r2]*nx[r2] + ny[r2]*ny[r2] + nz[r2]*nz[r2]);
        }
        __syncthreads();

        for (int ch = 0; ch < 8; ++ch) {
            // issue next chunk's loads early — latency hides under the scan
            if (ch < 7) {
#pragma unroll
                for (int r2 = 0; r2 < 4; ++r2) {
                    int ci = (ch + 1) * 1024 + t + r2 * 256;
                    nx[r2] = X[ci]; ny[r2] = X[NPTS + ci]; nz[r2] = X[2 * NPTS + ci];
                }
            }
            int i0 = 0;
            if (ch == 0) {
                float4 c = pts[lane];
                float dA = (qsqA + c.w) - 2.0f * (qxA * c.x + qyA * c.y + qzA * c.z);
                init9(dA, lane, kkdA, iddA);
                tauA = tau32((unsigned)__builtin_amdgcn_readlane((int)kkdA, 8));
                float dB = (qsqB + c.w) - 2.0f * (qxB * c.x + qyB * c.y + qzB * c.z);
                init9(dB, lane, kkdB, iddB);
                tauB = tau32((unsigned)__builtin_amdgcn_readlane((int)kkdB, 8));
                i0 = 1;
            }
            for (int i = i0; i < 16; ++i) {
                float4 c = pts[i * 64 + lane];
                float dA = (qsqA + c.w) - 2.0f * (qxA * c.x + qyA * c.y + qzA * c.z);
                float dB = (qsqB + c.w) - 2.0f * (qxB * c.x + qyB * c.y + qzB * c.z);
                const int base = ch * 1024 + i * 64;
                hits9(dA, base, tauA, kkdA, iddA);
                hits9(dB, base, tauB, kkdB, iddB);
            }
            __syncthreads();   // all waves done reading this chunk
            if (ch < 7) {
#pragma unroll
                for (int r2 = 0; r2 < 4; ++r2) {
                    int i2 = t + r2 * 256;
                    pts[i2] = make_float4(nx[r2], ny[r2], nz[r2],
                                          nx[r2]*nx[r2] + ny[r2]*ny[r2] + nz[r2]*nz[r2]);
                }
                __syncthreads();
            }
        }
        if (lane < 9) {
            int mA = iddA;
            mA = ((unsigned)mA < (unsigned)NPTS) ? mA : 0;
            idxg[qA * 9 + lane] = b * NPTS + mA;
            int mB = iddB;
            mB = ((unsigned)mB < (unsigned)NPTS) ? mB : 0;
            idxg[qB * 9 + lane] = b * NPTS + mB;
        }
    } else if (bx < 2560) {
        // --------------------------- conv12 -------------------------------
        bf16 (*P1t)[136] = (bf16 (*)[136])smem;
        const int w = threadIdx.x >> 6, lane = threadIdx.x & 63;
        const int q = lane >> 4, r = lane & 15;
        const int ptb = (bx - 2048) * 32;
        {
            f32x4 acc[2][2]; zacc(acc);
            const int ob = w * 32;
            mm32(acc, CV, 64, ptb, 64, FL, 32, ptb, W0p, 96, 96, ob);
#pragma unroll
            for (int to = 0; to < 2; ++to) {
                const int o = ob + to * 16 + r;
                float bs = b0[o];
                float gg = bn0[o], be = bn0[128 + o], mm = bn0[256 + o];
                float rs = 1.0f / sqrtf(bn0[384 + o] + 1e-5f);
#pragma unroll
                for (int tm = 0; tm < 2; ++tm) {
#pragma unroll
                    for (int rr = 0; rr < 4; ++rr) {
                        const int jl = tm * 16 + q * 4 + rr;
                        float v = acc[tm][to][rr] + bs;
                        v = (v - mm) * rs * gg + be;
                        v = v > 0.f ? v : 0.1f * v;
                        P1t[jl][o] = f2b(v);
                    }
                }
            }
        }
        __syncthreads();
        {
            f32x4 acc[2][2]; zacc(acc);
            const int ob = w * 32;
            mm32(acc, &P1t[0][0], 136, 0, 128, &P1t[0][0], 136, 0, W1, 128, 128, ob);
#pragma unroll
            for (int to = 0; to < 2; ++to) {
                const int o = ob + to * 16 + r;
                float bs = b1[o];
                float gg = bn1[o], be = bn1[128 + o], mm = bn1[256 + o];
                float rs = 1.0f / sqrtf(bn1[384 + o] + 1e-5f);
#pragma unroll
                for (int tm = 0; tm < 2; ++tm) {
#pragma unroll
                    for (int rr = 0; rr < 4; ++rr) {
                        const int jl = tm * 16 + q * 4 + rr;
                        float v = acc[tm][to][rr] + bs;
                        v = (v - mm) * rs * gg + be;
                        v = v > 0.f ? v : 0.1f * v;
                        P2[(size_t)(ptb + jl) * 128 + o] = f2b(v);
                    }
                }
            }
        }
    } else if (bx < 3584) {
        bf16 (*tile)[68] = (bf16 (*)[68])smem;
        int l = bx - 2560, x = l & 127, r2 = l >> 7;
        pack_body(tile, feats, 128, FE, 128, x * 64, (r2 & 3) * 32, r2 >> 2);
    } else if (bx < 4096) {
        bf16 (*tile)[68] = (bf16 (*)[68])smem;
        int l = bx - 3584, x = l & 127, r2 = l >> 7;
        pack_body(tile, points, 64, PT, 64, x * 64, (r2 & 1) * 32, r2 >> 1);
    } else {
        // --------- coarse = reg(cost_volume): 64 points/block --------------
        bf16 (*C1t)[72] = (bf16 (*)[72])smem;             // [64][72]
        bf16 (*C2t)[72] = (bf16 (*)[72])(smem + 9216);    // [64][72]
        const int w = threadIdx.x >> 6, lane = threadIdx.x & 63;
        const int q = lane >> 4, r = lane & 15;
        const int row0 = (w >> 1) * 32;
        const int pt0 = (bx - 4096) * 64 + row0;
        const int ob = (w & 1) * 32;
        {
            f32x4 acc[2][2]; zacc(acc);
            mm32(acc, CV, 64, pt0, 64, CV, 64, pt0, CW0, 64, 64, ob);
#pragma unroll
            for (int to = 0; to < 2; ++to) {
                const int o = ob + to * 16 + r;
                float gg = cbn0[o], be = cbn0[64 + o], mm = cbn0[128 + o];
                float rs = 1.0f / sqrtf(cbn0[192 + o] + 1e-5f);
#pragma unroll
                for (int tm = 0; tm < 2; ++tm)
#pragma unroll
                    for (int rr = 0; rr < 4; ++rr) {
                        const int jl = tm * 16 + q * 4 + rr;
                        float v = acc[tm][to][rr];
                        v = (v - mm) * rs * gg + be;
                        C1t[row0 + jl][o] = f2b(fmaxf(v, 0.f));
                    }
            }
        }
        __syncthreads();
        {
            f32x4 acc[2][2]; zacc(acc);
            mm32(acc, &C1t[0][0], 72, row0, 64, &C1t[0][0], 72, row0, CW1, 64, 64, ob);
#pragma unroll
            for (int to = 0; to < 2; ++to) {
                const int o = ob + to * 16 + r;
                float gg = cbn1[o], be = cbn1[64 + o], mm = cbn1[128 + o];
                float rs = 1.0f / sqrtf(cbn1[192 + o] + 1e-5f);
#pragma unroll
                for (int tm = 0; tm < 2; ++tm)
#pragma unroll
                    for (int rr = 0; rr < 4; ++rr) {
                        const int jl = tm * 16 + q * 4 + rr;
                        float v = acc[tm][to][rr];
                        v = (v - mm) * rs * gg + be;
                        C2t[row0 + jl][o] = f2b(fmaxf(v, 0.f));
                    }
            }
        }
        __syncthreads();
        if (threadIdx.x < 64) {
            const int jl = threadIdx.x;
            const int j = (bx - 4096) * 64 + jl;
            float dc = 0.f;
#pragma unroll
            for (int c = 0; c < 64; ++c) dc += cw2[c] * b2f(C2t[jl][c]);
            float coarse = (dc - cbn2[2]) / sqrtf(cbn2[3] + 1e-5f) * cbn2[0] + cbn2[1];
            coarseG[j] = fmaxf(coarse, 0.f);
        }
    }
}

// ------------------------------ K3: fused gather + row-local tail ----------
struct MRP {
    const bf16 *P2, *FE, *PT;
    const int  *idx;
    const bf16 *WZ, *WR, *WQ, *W2A, *W2B, *RW0, *RW1;
    const float *bz, *br, *bq, *b2a, *b2b;
    const float *rbn0, *rbn1;
    const float *rw2, *rbn2, *wfc, *bfc, *flow, *coarse;
    float* out;
};

// block = 32 points, 8 waves (512 thr). Stage 0: FE/PT tiles -> LDS + 9-NN
// gather-max (16B loads, one row/thread) -> X1t. Then zr (mm16x2) -> gq ->
// g2a -> g2b -> R1 -> R2 -> head; every mm operand reads LDS. Per-output
// accumulation chains bit-identical.
__global__ __launch_bounds__(512) void megarow(MRP p)
{
    __shared__ __align__(16) bf16 Zt[32][136], RHt[32][136], HPt[32][136], X1t[32][136];
    __shared__ __align__(16) bf16 FEt[32][136];
    __shared__ __align__(16) bf16 X2t[32][72], R1t[32][72], R2t[32][72], PTt[32][72];
    __shared__ int idxt[32][9];
    const int w = threadIdx.x >> 6, lane = threadIdx.x & 63;
    const int q = lane >> 4, r = lane & 15;
    const int ptb = blockIdx.x * 32;

    // stage 0a: idx tile + FE/PT tiles into LDS
    if (threadIdx.x < 288) {
        int jl = threadIdx.x / 9, k = threadIdx.x - jl * 9;
        int m = p.idx[(ptb + jl) * 9 + k];
        idxt[jl][k] = ((unsigned)m < (unsigned)MTOT) ? m : 0;
    }
    {
        const int row = threadIdx.x >> 4;
        const int c8 = (threadIdx.x & 15) * 8;
        *(bf16x8*)&FEt[row][c8] = *(const bf16x8*)(p.FE + (size_t)(ptb + row) * 128 + c8);
        const int c4 = (threadIdx.x & 15) * 4;
        *(bf16x4*)&PTt[row][c4] = *(const bf16x4*)(p.PT + (size_t)(ptb + row) * 64 + c4);
    }
    __syncthreads();
    // stage 0b: gather-max H tile (16B loads; same per-channel fmax chains)
    {
        const int c8 = (threadIdx.x & 15) * 8;
        const int jl = threadIdx.x >> 4;             // row 0..31
        float mx0 = -__builtin_inff(), mx1 = -__builtin_inff();
        float mx2 = -__builtin_inff(), mx3 = -__builtin_inff();
        float mx4 = -__builtin_inff(), mx5 = -__builtin_inff();
        float mx6 = -__builtin_inff(), mx7 = -__builtin_inff();
#pragma unroll
        for (int k = 0; k < 9; ++k) {
            bf16x8 v = *(const bf16x8*)(p.P2 + (size_t)idxt[jl][k] * 128 + c8);
            mx0 = fmaxf(mx0, b2f(v[0]));
            mx1 = fmaxf(mx1, b2f(v[1]));
            mx2 = fmaxf(mx2, b2f(v[2]));
            mx3 = fmaxf(mx3, b2f(v[3]));
            mx4 = fmaxf(mx4, b2f(v[4]));
            mx5 = fmaxf(mx5, b2f(v[5]));
            mx6 = fmaxf(mx6, b2f(v[6]));
            mx7 = fmaxf(mx7, b2f(v[7]));
        }
        bf16x8 st;
        st[0] = f2b(mx0); st[1] = f2b(mx1); st[2] = f2b(mx2); st[3] = f2b(mx3);
        st[4] = f2b(mx4); st[5] = f2b(mx5); st[6] = f2b(mx6); st[7] = f2b(mx7);
        *(bf16x8*)&X1t[jl][c8] = st;
    }
    __syncthreads();

    // D: GRU gates z, r.h  (X1t == H tile); A loaded once per wave, all LDS
    {
        const int ob = w * 16;
        f32x4 acc[2], acc2[2]; zacc2(acc); zacc2(acc2);
        mm16x2(acc, acc2, &X1t[0][0], 136, 0, 128, &FEt[0][0], 136, 0,
               p.WZ, p.WR, 256, 256, ob);
        const int o = ob + r;
        const float bsz = p.bz[o];
#pragma unroll
        for (int tm = 0; tm < 2; ++tm)
#pragma unroll
            for (int rr = 0; rr < 4; ++rr) {
                const int jl = tm * 16 + q * 4 + rr;
                float v = acc[tm][rr] + bsz;
                Zt[jl][o] = f2b(1.0f / (1.0f + expf(-v)));
            }
        const float bsr = p.br[o];
#pragma unroll
        for (int tm = 0; tm < 2; ++tm)
#pragma unroll
            for (int rr = 0; rr < 4; ++rr) {
                const int jl = tm * 16 + q * 4 + rr;
                float v = acc2[tm][rr] + bsr;
                v = 1.0f / (1.0f + expf(-v));
                RHt[jl][o] = f2b(v * b2f(X1t[jl][o]));
            }
    }
    __syncthreads();
    // E: q = tanh(...); h' = (1-z)h + z q  -> HPt
    {
        const int ob = w * 16;
        f32x4 acc[2]; zacc2(acc);
        mm16(acc, &RHt[0][0], 136, 0, 128, &FEt[0][0], 136, 0, p.WQ, 256, 256, ob);
        const int o = ob + r;
        const float bs = p.bq[o];
#pragma unroll
        for (int tm = 0; tm < 2; ++tm)
#pragma unroll
            for (int rr = 0; rr < 4; ++rr) {
                const int jl = tm * 16 + q * 4 + rr;
                float v = acc[tm][rr] + bs;
                float qv = tanhf(v);
                float z = b2f(Zt[jl][o]);
                float h = b2f(X1t[jl][o]);
                HPt[jl][o] = f2b((1.0f - z) * h + z * qv);
            }
    }
    __syncthreads();
    // F: x1 = lrelu(w2a . [points | h'])  (overwrites X1t — H dead now)
    {
        const int ob = w * 16;
        f32x4 acc[2]; zacc2(acc);
        mm16(acc, &PTt[0][0], 72, 0, 64, &HPt[0][0], 136, 0, p.W2A, 192, 192, ob);
        const int o = ob + r;
        const float bs = p.b2a[o];
#pragma unroll
        for (int tm = 0; tm < 2; ++tm)
#pragma unroll
            for (int rr = 0; rr < 4; ++rr) {
                const int jl = tm * 16 + q * 4 + rr;
                float v = acc[tm][rr] + bs;
                X1t[jl][o] = f2b(v > 0.f ? v : 0.1f * v);
            }
    }
    __syncthreads();
    // G: waves 0-3: x2 = lrelu(w2b . x1) (+ out x-section)
    if (w < 4) {
        const int ob = w * 16;
        f32x4 acc[2]; zacc2(acc);
        mm16(acc, &X1t[0][0], 136, 0, 128, &X1t[0][0], 136, 0, p.W2B, 128, 128, ob);
        const int o = ob + r;
        const float bs = p.b2b[o];
#pragma unroll
        for (int tm = 0; tm < 2; ++tm)
#pragma unroll
            for (int rr = 0; rr < 4; ++rr) {
                const int jl = tm * 16 + q * 4 + rr;
                float v = acc[tm][rr] + bs;
                v = v > 0.f ? v : 0.1f * v;
                X2t[jl][o] = f2b(v);
                const int j = ptb + jl, bb = j >> 13, nn = j & (NPTS - 1);
                p.out[(size_t)bb * 64 * NPTS + (size_t)o * NPTS + nn] = v;
            }
    }
    __syncthreads();
    // H: waves 0-3: R1 = reg(x2)
    if (w < 4) {
        const int ob = w * 16;
        f32x4 acc[2]; zacc2(acc);
        mm16(acc, &X2t[0][0], 72, 0, 64, &X2t[0][0], 72, 0, p.RW0, 64, 64, ob);
        const int o = ob + r;
        float gg = p.rbn0[o], be = p.rbn0[64 + o], mm = p.rbn0[128 + o];
        float rs = 1.0f / sqrtf(p.rbn0[192 + o] + 1e-5f);
#pragma unroll
        for (int tm = 0; tm < 2; ++tm)
#pragma unroll
            for (int rr = 0; rr < 4; ++rr) {
                const int jl = tm * 16 + q * 4 + rr;
                float v = acc[tm][rr];
                v = (v - mm) * rs * gg + be;
                R1t[jl][o] = f2b(fmaxf(v, 0.f));
            }
    }
    __syncthreads();
    // I: waves 0-3: R2 = reg(R1)
    if (w < 4) {
        const int ob = w * 16;
        f32x4 acc[2]; zacc2(acc);
        mm16(acc, &R1t[0][0], 72, 0, 64, &R1t[0][0], 72, 0, p.RW1, 64, 64, ob);
        const int o = ob + r;
        float gg = p.rbn1[o], be = p.rbn1[64 + o], mm = p.rbn1[128 + o];
        float rs = 1.0f / sqrtf(p.rbn1[192 + o] + 1e-5f);
#pragma unroll
        for (int tm = 0; tm < 2; ++tm)
#pragma unroll
            for (int rr = 0; rr < 4; ++rr) {
                const int jl = tm * 16 + q * 4 + rr;
                float v = acc[tm][rr];
                v = (v - mm) * rs * gg + be;
                R2t[jl][o] = f2b(fmaxf(v, 0.f));
            }
    }
    __syncthreads();
    // J: head fuse (threads 0..31, one point each)
    if (threadIdx.x < 32) {
        const int jl = threadIdx.x, j = ptb + jl;
        const int b = j >> 13, n = j & (NPTS - 1);
        float dr = 0.f, p0 = 0.f, p1 = 0.f, p2 = 0.f;
#pragma unroll
        for (int c = 0; c < 64; ++c) {
            float x = b2f(X2t[jl][c]);
            dr += p.rw2[c] * b2f(R2t[jl][c]);
            p0 += p.wfc[c] * x;
            p1 += p.wfc[64 + c] * x;
            p2 += p.wfc[128 + c] * x;
        }
        float refine = (dr - p.rbn2[2]) / sqrtf(p.rbn2[3] + 1e-5f) * p.rbn2[0] + p.rbn2[1];
        refine = fmaxf(refine, 0.f);
        const float coarse = p.coarse[j];
        p0 += p.bfc[0]; p1 += p.bfc[1]; p2 += p.bfc[2];
        const float f0 = p.flow[(size_t)b * 3 * NPTS + n];
        const float f1 = p.flow[(size_t)b * 3 * NPTS + NPTS + n];
        const float f2v = p.flow[(size_t)b * 3 * NPTS + 2 * NPTS + n];
        float o0 = fminf(fmaxf(coarse * f0 + refine * p0, -20.f), 20.f);
        float o1 = fminf(fmaxf(coarse * f1 + refine * p1, -20.f), 20.f);
        float o2 = fminf(fmaxf(coarse * f2v + refine * p2, -20.f), 20.f);
        float* ro = p.out + 1048576;
        ro[(size_t)b * 3 * NPTS + n] = o0;
        ro[(size_t)b * 3 * NPTS + NPTS + n] = o1;
        ro[(size_t)b * 3 * NPTS + 2 * NPTS + n] = o2;
    }
}

// -------------------------------------------------------------- launch -----
// Workspace (18,767,872 B):
//   W0p @0 | WTS @24,576 | idxg @352,256 | CV @942,080 | FL @3,039,232
//   FE @4,087,808 | PT @8,282,112 | P2 @10,379,264 | coarse @14,573,568
extern "C" void kernel_launch(void* const* d_in, const int* in_sizes, int n_in,
                              void* d_out, int out_size, void* d_ws, size_t ws_size,
                              hipStream_t stream)
{
    static const int EXP[35] = {
        49152, 1048576, 1048576, 2097152, 49152,
        8576, 128, 512, 16384, 128, 512,
        32768, 128, 32768, 128, 32768, 128,
        24576, 128, 8192, 64, 192, 3,
        4096, 256, 4096, 256, 64, 4,
        4096, 256, 4096, 256, 64, 4 };
    float code = 0.f;
    if (n_in != 35) code = 900.f;
    else if (out_size != 1097728) code = 950.f;
    else if (ws_size < 18767872u) code = 980.f;
    else { for (int i = 0; i < 35; ++i) if (in_sizes[i] != EXP[i]) { code = 1000.f + 4.f * i; break; } }
    if (code != 0.f) { diag_k<<<dim3(1), dim3(64), 0, stream>>>((float*)d_out, code); return; }

    const float* xyz    = (const float*)d_in[0];
    const float* points = (const float*)d_in[1];
    const float* cost   = (const float*)d_in[2];
    const float* feats  = (const float*)d_in[3];
    const float* flow   = (const float*)d_in[4];
    const float* w0     = (const float*)d_in[5];
    const float* b0     = (const float*)d_in[6];
    const float* bn0    = (const float*)d_in[7];
    const float* w1     = (const float*)d_in[8];
    const float* b1     = (const float*)d_in[9];
    const float* bn1    = (const float*)d_in[10];
    const float* wz     = (const float*)d_in[11];
    const float* bz     = (const float*)d_in[12];
    const float* wr     = (const float*)d_in[13];
    const float* br     = (const float*)d_in[14];
    const float* wq     = (const float*)d_in[15];
    const float* bq     = (const float*)d_in[16];
    const float* w2a    = (const float*)d_in[17];
    const float* b2a    = (const float*)d_in[18];
    const float* w2b    = (const float*)d_in[19];
    const float* b2b    = (const float*)d_in[20];
    const float* wfc    = (const float*)d_in[21];
    const float* bfc    = (const float*)d_in[22];
    const float* rw0    = (const float*)d_in[23];
    const float* rbn0   = (const float*)d_in[24];
    const float* rw1    = (const float*)d_in[25];
    const float* rbn1   = (const float*)d_in[26];
    const float* rw2    = (const float*)d_in[27];
    const float* rbn2   = (const float*)d_in[28];
    const float* cw0    = (const float*)d_in[29];
    const float* cbn0   = (const float*)d_in[30];
    const float* cw1    = (const float*)d_in[31];
    const float* cbn1   = (const float*)d_in[32];
    const float* cw2    = (const float*)d_in[33];
    const float* cbn2   = (const float*)d_in[34];

    char* ws = (char*)d_ws;
    bf16*  W0p  = (bf16*)(ws + 0);
    bf16*  WTS  = (bf16*)(ws + 24576);
    int*   idxg = (int*) (ws + 352256);
    bf16*  CV   = (bf16*)(ws + 942080);
    bf16*  FL   = (bf16*)(ws + 3039232);
    bf16*  FE   = (bf16*)(ws + 4087808);
    bf16*  PT   = (bf16*)(ws + 8282112);
    bf16*  P2   = (bf16*)(ws + 10379264);
    float* CO   = (float*)(ws + 14573568);

    bf16* W1  = WTS;
    bf16* WZ  = WTS + 16384;
    bf16* WR  = WTS + 49152;
    bf16* WQ  = WTS + 81920;
    bf16* W2A = WTS + 114688;
    bf16* W2B = WTS + 139264;
    bf16* RW0 = WTS + 147456;
    bf16* RW1 = WTS + 151552;
    bf16* CW0 = WTS + 155648;
    bf16* CW1 = WTS + 159744;

    float* out = (float*)d_out;

    /*1*/ pack_a<<<dim3(1456), dim3(256), 0, stream>>>(
              w0, w1, wz, wr, wq, w2a, w2b, rw0, rw1, cw0, cw1,
              cost, flow, W0p, WTS, CV, FL);
    /*2*/ knn_conv_packb<<<dim3(4352), dim3(256), 0, stream>>>(
              xyz, feats, points, CV, FL, W0p, W1, CW0, CW1,
              b0, bn0, b1, bn1, cbn0, cbn1, cw2, cbn2,
              FE, PT, P2, idxg, CO);
    /*3*/ MRP mp;
          mp.P2 = P2; mp.FE = FE; mp.PT = PT; mp.idx = idxg;
          mp.WZ = WZ; mp.WR = WR; mp.WQ = WQ; mp.W2A = W2A; mp.W2B = W2B;
          mp.RW0 = RW0; mp.RW1 = RW1;
          mp.bz = bz; mp.br = br; mp.bq = bq; mp.b2a = b2a; mp.b2b = b2b;
          mp.rbn0 = rbn0; mp.rbn1 = rbn1;
          mp.rw2 = rw2; mp.rbn2 = rbn2;
          mp.wfc = wfc; mp.bfc = bfc; mp.flow = flow; mp.coarse = CO;
          mp.out = out;
          megarow<<<dim3(512), dim3(512), 0, stream>>>(mp);

    (void)n_in;
}